// Round 17
// baseline (350.903 us; speedup 1.0000x reference)
//
#include <hip/hip_runtime.h>
#include <hip/hip_bf16.h>

typedef __hip_bfloat16 bf16;

#define DEPS 1e-16f
#define CAP 32
#define OVF_MAX 131072

__device__ __forceinline__ float bfu_lo(unsigned u) { return __uint_as_float(u << 16); }
__device__ __forceinline__ float bfu_hi(unsigned u) { return __uint_as_float(u & 0xffff0000u); }

// bucket entry: (s << 15) | q, wt = q/8192 - 1.1, q in [0,32767]
__device__ __forceinline__ float dec_wt(unsigned u) {
    return (float)(u & 32767u) * (1.f / 8192.f) - 1.1f;
}

// h1 = x@W1 (bf16) + asrc/adst. 32 nodes/block, 4 waves x 8 nodes. (R16 proven)
__global__ __launch_bounds__(256) void f_gemm1(
    const float* __restrict__ x, const float* __restrict__ W1,
    const float* __restrict__ a_src, const float* __restrict__ a_dst,
    bf16* __restrict__ h1, float* __restrict__ asrc, float* __restrict__ adst,
    int N)
{
    __shared__ __align__(16) float Wl[128 * 64];   // 32 KB
    __shared__ __align__(16) float xl[32 * 128];   // 16 KB
    int tid = threadIdx.x;
    for (int i = tid; i < 2048; i += 256)
        ((float4*)Wl)[i] = ((const float4*)W1)[i];
    int n0 = blockIdx.x * 32;
    for (int i = tid; i < 1024; i += 256) {
        int n = n0 + (i >> 5);
        float4 v = {0.f, 0.f, 0.f, 0.f};
        if (n < N) v = ((const float4*)x)[(size_t)n * 32 + (i & 31)];
        ((float4*)xl)[i] = v;
    }
    __syncthreads();
    int w = tid >> 6, c = tid & 63;
    float sa = a_src[c], da = a_dst[c];
    float acc[8] = {0.f, 0.f, 0.f, 0.f, 0.f, 0.f, 0.f, 0.f};
    for (int k4 = 0; k4 < 32; ++k4) {
        float w0 = Wl[(4 * k4 + 0) * 64 + c];
        float w1 = Wl[(4 * k4 + 1) * 64 + c];
        float w2 = Wl[(4 * k4 + 2) * 64 + c];
        float w3 = Wl[(4 * k4 + 3) * 64 + c];
        #pragma unroll
        for (int i = 0; i < 8; ++i) {
            float4 xv = ((const float4*)(xl + (w * 8 + i) * 128))[k4];
            acc[i] = fmaf(xv.x, w0, fmaf(xv.y, w1,
                     fmaf(xv.z, w2, fmaf(xv.w, w3, acc[i]))));
        }
    }
    #pragma unroll
    for (int i = 0; i < 8; ++i) {
        int n = n0 + w * 8 + i;
        float a = acc[i];
        float ps = a * sa, pd = a * da;
        #pragma unroll
        for (int o = 32; o; o >>= 1) {
            ps += __shfl_xor(ps, o);
            pd += __shfl_xor(pd, o);
        }
        if (n < N) {
            h1[(size_t)n * 64 + c] = __float2bfloat16(a);
            if (c == 0) { asrc[n] = ps; adst[n] = pd; }
        }
    }
}

// ONE-KERNEL CSR: fixed-capacity bucket scatter (1 atomic + 1 store per edge).
// Rows at bkt[d*CAP]; rare deg>CAP entries go to a tiny overflow list.
__global__ __launch_bounds__(256) void f_bucket(
    const int* __restrict__ srcv, const int* __restrict__ dstv,
    const float* __restrict__ ew, int* __restrict__ cnt,
    unsigned* __restrict__ bkt, uint2* __restrict__ ovf,
    int* __restrict__ ovfn, int E, int T)
{
    int e = blockIdx.x * 256 + threadIdx.x;
    if (e >= T) return;
    int s, d; float wt;
    if (e < E) { s = srcv[e]; d = dstv[e]; wt = 1.f - 1.f / ew[e]; }
    else       { s = d = e - E; wt = 0.f; }
    unsigned q = (unsigned)((wt + 1.1f) * 8192.f + 0.5f);
    unsigned entry = ((unsigned)s << 15) | q;
    int pos = atomicAdd(&cnt[d], 1);
    if (pos < CAP) {
        bkt[(size_t)d * CAP + pos] = entry;
    } else {
        int o = atomicAdd(ovfn, 1);
        if (o < OVF_MAX) { uint2 v; v.x = (unsigned)d; v.y = entry; ovf[o] = v; }
    }
}

// fused layer-1 aggregate + slim layer-2 epilogue. One wave per dst.
// Row = bkt[d*CAP], len = min(cnt[d], CAP) <= 64 -> single chunk.
// Overflow scanned only when cnt[d] > CAP (~30 waves device-wide).
__global__ __launch_bounds__(256) void f_agg1(
    const int* __restrict__ cnt, const unsigned* __restrict__ bkt,
    const uint2* __restrict__ ovf, const int* __restrict__ ovfn,
    const float* __restrict__ asrc, const float* __restrict__ adst,
    const bf16* __restrict__ h1,
    const float* __restrict__ b1, const float* __restrict__ W2,
    const float* __restrict__ a2s, const float* __restrict__ a2d,
    float* __restrict__ h2p, float* __restrict__ ad2, int N)
{
    __shared__ __align__(16) float WxT[12][64];  // [output][channel], b128 reads
    __shared__ __align__(16) float b1l[64];
    __shared__ float2 eb[4][64];                 // wave-private slices
    int tid = threadIdx.x;
    if (tid < 64) {
        float us = 0.f, ud = 0.f;
        #pragma unroll
        for (int c = 0; c < 7; ++c) {
            float wv = W2[tid * 7 + c];
            WxT[c][tid] = wv;
            us = fmaf(wv, a2s[c], us);
            ud = fmaf(wv, a2d[c], ud);
        }
        WxT[7][tid] = us;
        WxT[8][tid] = ud;
        WxT[9][tid] = 0.f; WxT[10][tid] = 0.f; WxT[11][tid] = 0.f;
        b1l[tid] = b1[tid];
    }
    __syncthreads();
    int d = blockIdx.x * 4 + (tid >> 6);
    int lane = tid & 63;
    if (d >= N) return;
    int lenf = cnt[d];
    int nc = min(lenf, CAP);
    size_t r0 = (size_t)d * CAP;
    float adv = adst[d];
    int g = lane >> 4, l16 = lane & 15;
    float2* ebw = eb[tid >> 6];
    float acc0 = 0.f, acc1 = 0.f, acc2 = 0.f, acc3 = 0.f, sm = 0.f;
    {
        float ea = 0.f; unsigned s = 0;
        if (lane < nc) {
            unsigned u = bkt[r0 + lane];
            s = u >> 15;
            float a = asrc[s] + adv;
            a = (a > 0.f) ? a : 0.2f * a;
            ea = __expf(a + dec_wt(u));
            sm += ea;
        }
        ebw[lane] = make_float2(ea, __uint_as_float(s));
        for (int j = 0; j < nc; j += 4) {
            float2 eq = ebw[j + g];              // same addr per 16-lane group
            float e = eq.x;
            unsigned sj = __float_as_uint(eq.y); // padded slots have e==0
            uint2 hv = *(const uint2*)&h1[(size_t)sj * 64 + (l16 << 2)];
            acc0 = fmaf(e, bfu_lo(hv.x), acc0);
            acc1 = fmaf(e, bfu_hi(hv.x), acc1);
            acc2 = fmaf(e, bfu_lo(hv.y), acc2);
            acc3 = fmaf(e, bfu_hi(hv.y), acc3);
        }
    }
    if (lenf > CAP) {                            // rare overflow path
        int no = min(*ovfn, OVF_MAX);
        for (int i = g; i < no; i += 4) {        // entry i -> group i&3
            uint2 ov = ovf[i];
            if ((int)ov.x == d) {
                unsigned u = ov.y;
                unsigned s = u >> 15;
                float a = asrc[s] + adv;
                a = (a > 0.f) ? a : 0.2f * a;
                float ea = __expf(a + dec_wt(u));
                if (l16 == 0) sm += ea;          // count edge exactly once
                uint2 hv = *(const uint2*)&h1[(size_t)s * 64 + (l16 << 2)];
                acc0 = fmaf(ea, bfu_lo(hv.x), acc0);
                acc1 = fmaf(ea, bfu_hi(hv.x), acc1);
                acc2 = fmaf(ea, bfu_lo(hv.y), acc2);
                acc3 = fmaf(ea, bfu_hi(hv.y), acc3);
            }
        }
    }
    #pragma unroll
    for (int o = 32; o; o >>= 1) sm += __shfl_xor(sm, o);
    acc0 += __shfl_xor(acc0, 16); acc0 += __shfl_xor(acc0, 32);
    acc1 += __shfl_xor(acc1, 16); acc1 += __shfl_xor(acc1, 32);
    acc2 += __shfl_xor(acc2, 16); acc2 += __shfl_xor(acc2, 32);
    acc3 += __shfl_xor(acc3, 16); acc3 += __shfl_xor(acc3, 32);
    float inv = 1.f / (sm + DEPS);
    int c0 = 4 * l16;
    float4 bb = *(const float4*)&b1l[c0];
    float v0 = fmaxf(fmaf(acc0, inv, bb.x), 0.f);
    float v1 = fmaxf(fmaf(acc1, inv, bb.y), 0.f);
    float v2 = fmaxf(fmaf(acc2, inv, bb.z), 0.f);
    float v3 = fmaxf(fmaf(acc3, inv, bb.w), 0.f);
    int colb = g * 3;                     // g3 computes zero columns
    float4 w0 = *(const float4*)&WxT[colb][c0];
    float4 w1 = *(const float4*)&WxT[colb + 1][c0];
    float4 w2 = *(const float4*)&WxT[colb + 2][c0];
    float r0v = fmaf(v0, w0.x, fmaf(v1, w0.y, fmaf(v2, w0.z, v3 * w0.w)));
    float r1v = fmaf(v0, w1.x, fmaf(v1, w1.y, fmaf(v2, w1.z, v3 * w1.w)));
    float r2v = fmaf(v0, w2.x, fmaf(v1, w2.y, fmaf(v2, w2.z, v3 * w2.w)));
    #pragma unroll
    for (int o = 8; o; o >>= 1) {
        r0v += __shfl_xor(r0v, o);
        r1v += __shfl_xor(r1v, o);
        r2v += __shfl_xor(r2v, o);
    }
    if (l16 == 0) {
        float* row = &h2p[(size_t)d * 8];
        if (g == 0)      { row[0] = r0v; row[1] = r1v; row[2] = r2v; }
        else if (g == 1) { row[3] = r0v; row[4] = r1v; row[5] = r2v; }
        else if (g == 2) { row[6] = r0v; row[7] = r1v; ad2[d] = r2v; }
    }
}

// fused layer-2 aggregate + bias. 8 lanes per row, 8 rows per wave.
__global__ __launch_bounds__(256) void f_agg2(
    const int* __restrict__ cnt, const unsigned* __restrict__ bkt,
    const uint2* __restrict__ ovf, const int* __restrict__ ovfn,
    const float* __restrict__ h2p, const float* __restrict__ ad2,
    const float* __restrict__ b2, float* __restrict__ out, int N)
{
    __shared__ float b2l[7];
    if (threadIdx.x < 7) b2l[threadIdx.x] = b2[threadIdx.x];
    __syncthreads();
    int lane = threadIdx.x & 63;
    int wv = threadIdx.x >> 6;
    int grp = lane >> 3, l8 = lane & 7;
    int d = blockIdx.x * 32 + wv * 8 + grp;
    bool valid = d < N;
    int lenf = 0; float adv = 0.f;
    if (valid) { lenf = cnt[d]; adv = ad2[d]; }
    int nc = min(lenf, CAP);
    size_t r0 = (size_t)d * CAP;
    float sm = 0.f;
    float a0 = 0.f, a1 = 0.f, a2 = 0.f, a3 = 0.f, a4 = 0.f, a5 = 0.f, a6 = 0.f;
    for (int p = l8; p < nc; p += 8) {
        unsigned u = bkt[r0 + p];
        int s = (int)(u >> 15);
        const float* hr = &h2p[(size_t)s * 8];
        float4 A = *(const float4*)hr;
        float4 B = *(const float4*)(hr + 4);
        float a = B.w + adv;
        a = (a > 0.f) ? a : 0.2f * a;
        float ea = __expf(a + dec_wt(u));
        sm += ea;
        a0 = fmaf(ea, A.x, a0); a1 = fmaf(ea, A.y, a1);
        a2 = fmaf(ea, A.z, a2); a3 = fmaf(ea, A.w, a3);
        a4 = fmaf(ea, B.x, a4); a5 = fmaf(ea, B.y, a5);
        a6 = fmaf(ea, B.z, a6);
    }
    if (lenf > CAP) {                            // rare overflow path
        int no = min(*ovfn, OVF_MAX);
        for (int i = l8; i < no; i += 8) {       // entry i -> lane i&7
            uint2 ov = ovf[i];
            if ((int)ov.x == d) {
                unsigned u = ov.y;
                int s = (int)(u >> 15);
                const float* hr = &h2p[(size_t)s * 8];
                float4 A = *(const float4*)hr;
                float4 B = *(const float4*)(hr + 4);
                float a = B.w + adv;
                a = (a > 0.f) ? a : 0.2f * a;
                float ea = __expf(a + dec_wt(u));
                sm += ea;
                a0 = fmaf(ea, A.x, a0); a1 = fmaf(ea, A.y, a1);
                a2 = fmaf(ea, A.z, a2); a3 = fmaf(ea, A.w, a3);
                a4 = fmaf(ea, B.x, a4); a5 = fmaf(ea, B.y, a5);
                a6 = fmaf(ea, B.z, a6);
            }
        }
    }
    #pragma unroll
    for (int o = 4; o; o >>= 1) {
        sm += __shfl_xor(sm, o);
        a0 += __shfl_xor(a0, o); a1 += __shfl_xor(a1, o);
        a2 += __shfl_xor(a2, o); a3 += __shfl_xor(a3, o);
        a4 += __shfl_xor(a4, o); a5 += __shfl_xor(a5, o);
        a6 += __shfl_xor(a6, o);
    }
    if (valid && l8 < 7) {
        float inv = 1.f / (sm + DEPS);
        float val = (l8 < 4) ? ((l8 < 2) ? (l8 ? a1 : a0) : ((l8 == 2) ? a2 : a3))
                             : ((l8 < 6) ? ((l8 == 4) ? a4 : a5) : a6);
        out[(size_t)d * 7 + l8] = fmaf(val, inv, b2l[l8]);
    }
}

// ============================== HOST ======================================

extern "C" void kernel_launch(void* const* d_in, const int* in_sizes, int n_in,
                              void* d_out, int out_size, void* d_ws, size_t ws_size,
                              hipStream_t stream) {
    const float* x   = (const float*)d_in[0];
    const int*   ei  = (const int*)d_in[1];
    const float* ew  = (const float*)d_in[2];
    const float* W1  = (const float*)d_in[3];
    const float* as1 = (const float*)d_in[4];
    const float* ad1 = (const float*)d_in[5];
    const float* b1  = (const float*)d_in[6];
    const float* W2  = (const float*)d_in[7];
    const float* a2s = (const float*)d_in[8];
    const float* a2d = (const float*)d_in[9];
    const float* b2  = (const float*)d_in[10];

    int N = in_sizes[0] / 128;
    int E = in_sizes[1] / 2;
    int T = E + N;
    const int* srcv = ei;
    const int* dstv = ei + E;
    float* out = (float*)d_out;

    int gT = (T + 255) / 256;

    // workspace (256B aligned): ~31.45 MB (under proven 31.66 MB fit)
    size_t A = 0;
    auto take = [&](size_t b) { size_t o = A; A = (A + b + 255) & ~(size_t)255; return o; };
    size_t o_h1   = take((size_t)N * 64 * 2);       // 12.8 MB
    size_t o_bkt  = take((size_t)N * CAP * 4);      // 12.8 MB
    size_t o_h2p  = take((size_t)N * 8 * 4);        //  3.2 MB padded (+as2)
    size_t o_ovf  = take((size_t)OVF_MAX * 8);      //  1.0 MB
    size_t o_cnt  = take((size_t)N * 4);            //  0.4 MB (cnt)
    size_t o_ovfn = take(256);                      //  (contiguous after cnt)
    size_t o_asrc = take((size_t)N * 4);
    size_t o_adst = take((size_t)N * 4);
    size_t o_ad2  = take((size_t)N * 4);

    char* base = (char*)d_ws;
    bf16*     h1   = (bf16*)(base + o_h1);
    unsigned* bkt  = (unsigned*)(base + o_bkt);
    float*    h2p  = (float*)(base + o_h2p);
    uint2*    ovf  = (uint2*)(base + o_ovf);
    int*      cnt  = (int*)(base + o_cnt);
    int*      ovfn = (int*)(base + o_ovfn);
    float*    asrc = (float*)(base + o_asrc);
    float*    adst = (float*)(base + o_adst);
    float*    ad2  = (float*)(base + o_ad2);

    // zero cnt + ovfn in one memset (contiguous)
    hipMemsetAsync(cnt, 0, (size_t)N * 4 + 256, stream);
    f_bucket<<<gT, 256, 0, stream>>>(srcv, dstv, ew, cnt, bkt, ovf, ovfn, E, T);
    f_gemm1<<<(N + 31) / 32, 256, 0, stream>>>(x, W1, as1, ad1, h1, asrc, adst, N);
    f_agg1<<<(N + 3) / 4, 256, 0, stream>>>(cnt, bkt, ovf, ovfn, asrc, adst, h1,
                                            b1, W2, a2s, a2d, h2p, ad2, N);
    f_agg2<<<(N + 31) / 32, 256, 0, stream>>>(cnt, bkt, ovf, ovfn, h2p, ad2, b2, out, N);
}

// Round 18
// 323.910 us; speedup vs baseline: 1.0833x; 1.0833x over previous
//
#include <hip/hip_runtime.h>
#include <hip/hip_bf16.h>

typedef __hip_bfloat16 bf16;

#define DEPS 1e-16f
#define CAP 32
#define OVF_MAX 131072

__device__ __forceinline__ float bfu_lo(unsigned u) { return __uint_as_float(u << 16); }
__device__ __forceinline__ float bfu_hi(unsigned u) { return __uint_as_float(u & 0xffff0000u); }

// bucket entry: (s << 15) | q, wt = q/8192 - 1.1, q in [0,32767]
__device__ __forceinline__ float dec_wt(unsigned u) {
    return (float)(u & 32767u) * (1.f / 8192.f) - 1.1f;
}

// h1 = x@W1 (bf16) + asrc/adst. 32 nodes/block, 4 waves x 8 nodes. (proven)
__global__ __launch_bounds__(256) void f_gemm1(
    const float* __restrict__ x, const float* __restrict__ W1,
    const float* __restrict__ a_src, const float* __restrict__ a_dst,
    bf16* __restrict__ h1, float* __restrict__ asrc, float* __restrict__ adst,
    int N)
{
    __shared__ __align__(16) float Wl[128 * 64];   // 32 KB
    __shared__ __align__(16) float xl[32 * 128];   // 16 KB
    int tid = threadIdx.x;
    for (int i = tid; i < 2048; i += 256)
        ((float4*)Wl)[i] = ((const float4*)W1)[i];
    int n0 = blockIdx.x * 32;
    for (int i = tid; i < 1024; i += 256) {
        int n = n0 + (i >> 5);
        float4 v = {0.f, 0.f, 0.f, 0.f};
        if (n < N) v = ((const float4*)x)[(size_t)n * 32 + (i & 31)];
        ((float4*)xl)[i] = v;
    }
    __syncthreads();
    int w = tid >> 6, c = tid & 63;
    float sa = a_src[c], da = a_dst[c];
    float acc[8] = {0.f, 0.f, 0.f, 0.f, 0.f, 0.f, 0.f, 0.f};
    for (int k4 = 0; k4 < 32; ++k4) {
        float w0 = Wl[(4 * k4 + 0) * 64 + c];
        float w1 = Wl[(4 * k4 + 1) * 64 + c];
        float w2 = Wl[(4 * k4 + 2) * 64 + c];
        float w3 = Wl[(4 * k4 + 3) * 64 + c];
        #pragma unroll
        for (int i = 0; i < 8; ++i) {
            float4 xv = ((const float4*)(xl + (w * 8 + i) * 128))[k4];
            acc[i] = fmaf(xv.x, w0, fmaf(xv.y, w1,
                     fmaf(xv.z, w2, fmaf(xv.w, w3, acc[i]))));
        }
    }
    #pragma unroll
    for (int i = 0; i < 8; ++i) {
        int n = n0 + w * 8 + i;
        float a = acc[i];
        float ps = a * sa, pd = a * da;
        #pragma unroll
        for (int o = 32; o; o >>= 1) {
            ps += __shfl_xor(ps, o);
            pd += __shfl_xor(pd, o);
        }
        if (n < N) {
            h1[(size_t)n * 64 + c] = __float2bfloat16(a);
            if (c == 0) { asrc[n] = ps; adst[n] = pd; }
        }
    }
}

// in-degree histogram; records each edge's rank (atomic return, full MLP).
__global__ __launch_bounds__(256) void f_hist(
    const int* __restrict__ dstv, int* __restrict__ cnt,
    int* __restrict__ rank, int E, int T)
{
    int e = blockIdx.x * 256 + threadIdx.x;
    if (e >= T) return;
    int d = (e < E) ? dstv[e] : (e - E);
    rank[e] = atomicAdd(&cnt[d], 1);
}

// ATOMIC-FREE bucket scatter: pos = rank[e], fixed row base d*CAP.
// Independent stores -> full memory-level parallelism. No scans needed.
__global__ __launch_bounds__(256) void f_scatB(
    const int* __restrict__ srcv, const int* __restrict__ dstv,
    const float* __restrict__ ew, const int* __restrict__ rank,
    unsigned* __restrict__ bkt, uint2* __restrict__ ovf,
    int* __restrict__ ovfn, int E, int T)
{
    int e = blockIdx.x * 256 + threadIdx.x;
    if (e >= T) return;
    int s, d; float wt;
    if (e < E) { s = srcv[e]; d = dstv[e]; wt = 1.f - 1.f / ew[e]; }
    else       { s = d = e - E; wt = 0.f; }
    unsigned q = (unsigned)((wt + 1.1f) * 8192.f + 0.5f);
    unsigned entry = ((unsigned)s << 15) | q;
    int pos = rank[e];
    if (pos < CAP) {
        bkt[(size_t)d * CAP + pos] = entry;
    } else {
        int o = atomicAdd(ovfn, 1);      // ~tens of edges device-wide
        if (o < OVF_MAX) { uint2 v; v.x = (unsigned)d; v.y = entry; ovf[o] = v; }
    }
}

// fused layer-1 aggregate + slim layer-2 epilogue. One wave per dst.
// 8-lane groups: lane owns 8 channels (one uint4 = 16B of h1 row);
// 8 edges in flight per j-step. Epilogue: 2 outputs per group from
// WxT[16][68] (rows 0..6=W2 cols, 7=us, 8=ud, 9..15=0; stride 68).
__global__ __launch_bounds__(256) void f_agg1(
    const int* __restrict__ cnt, const unsigned* __restrict__ bkt,
    const uint2* __restrict__ ovf, const int* __restrict__ ovfn,
    const float* __restrict__ asrc, const float* __restrict__ adst,
    const bf16* __restrict__ h1,
    const float* __restrict__ b1, const float* __restrict__ W2,
    const float* __restrict__ a2s, const float* __restrict__ a2d,
    float* __restrict__ h2p, float* __restrict__ ad2, int N)
{
    __shared__ __align__(16) float WxT[16][68];  // 4.25 KB
    __shared__ __align__(16) float b1l[64];
    __shared__ float2 eb[4][64];                 // wave-private slices
    int tid = threadIdx.x;
    if (tid < 64) {
        float us = 0.f, ud = 0.f;
        #pragma unroll
        for (int c = 0; c < 7; ++c) {
            float wv = W2[tid * 7 + c];
            WxT[c][tid] = wv;
            us = fmaf(wv, a2s[c], us);
            ud = fmaf(wv, a2d[c], ud);
        }
        WxT[7][tid] = us;
        WxT[8][tid] = ud;
        #pragma unroll
        for (int r = 9; r < 16; ++r) WxT[r][tid] = 0.f;
        b1l[tid] = b1[tid];
    }
    __syncthreads();
    int d = blockIdx.x * 4 + (tid >> 6);
    int lane = tid & 63;
    if (d >= N) return;
    int lenf = cnt[d];
    int nc = min(lenf, CAP);
    size_t r0 = (size_t)d * CAP;
    float adv = adst[d];
    int g8 = lane >> 3, l8 = lane & 7;
    float2* ebw = eb[tid >> 6];
    float acc[8] = {0.f, 0.f, 0.f, 0.f, 0.f, 0.f, 0.f, 0.f};
    float sm = 0.f;
    {
        float ea = 0.f; unsigned s = 0;
        if (lane < nc) {
            unsigned u = bkt[r0 + lane];
            s = u >> 15;
            float a = asrc[s] + adv;
            a = (a > 0.f) ? a : 0.2f * a;
            ea = __expf(a + dec_wt(u));
            sm += ea;
        }
        ebw[lane] = make_float2(ea, __uint_as_float(s));
        for (int j = 0; j < nc; j += 8) {
            float2 eq = ebw[j + g8];             // 8 addrs, 8-lane broadcast
            float e = eq.x;                      // padded slots have e==0
            unsigned sj = __float_as_uint(eq.y);
            uint4 hv = *(const uint4*)&h1[(size_t)sj * 64 + (l8 << 3)];
            acc[0] = fmaf(e, bfu_lo(hv.x), acc[0]);
            acc[1] = fmaf(e, bfu_hi(hv.x), acc[1]);
            acc[2] = fmaf(e, bfu_lo(hv.y), acc[2]);
            acc[3] = fmaf(e, bfu_hi(hv.y), acc[3]);
            acc[4] = fmaf(e, bfu_lo(hv.z), acc[4]);
            acc[5] = fmaf(e, bfu_hi(hv.z), acc[5]);
            acc[6] = fmaf(e, bfu_lo(hv.w), acc[6]);
            acc[7] = fmaf(e, bfu_hi(hv.w), acc[7]);
        }
    }
    if (lenf > CAP) {                            // rare overflow path
        int no = min(*ovfn, OVF_MAX);
        for (int i = g8; i < no; i += 8) {       // entry i -> group i&7
            uint2 ov = ovf[i];
            if ((int)ov.x == d) {
                unsigned u = ov.y;
                unsigned s = u >> 15;
                float a = asrc[s] + adv;
                a = (a > 0.f) ? a : 0.2f * a;
                float ea = __expf(a + dec_wt(u));
                if (l8 == 0) sm += ea;           // count edge exactly once
                uint4 hv = *(const uint4*)&h1[(size_t)s * 64 + (l8 << 3)];
                acc[0] = fmaf(ea, bfu_lo(hv.x), acc[0]);
                acc[1] = fmaf(ea, bfu_hi(hv.x), acc[1]);
                acc[2] = fmaf(ea, bfu_lo(hv.y), acc[2]);
                acc[3] = fmaf(ea, bfu_hi(hv.y), acc[3]);
                acc[4] = fmaf(ea, bfu_lo(hv.z), acc[4]);
                acc[5] = fmaf(ea, bfu_hi(hv.z), acc[5]);
                acc[6] = fmaf(ea, bfu_lo(hv.w), acc[6]);
                acc[7] = fmaf(ea, bfu_hi(hv.w), acc[7]);
            }
        }
    }
    #pragma unroll
    for (int o = 32; o; o >>= 1) sm += __shfl_xor(sm, o);
    #pragma unroll
    for (int k = 0; k < 8; ++k) {
        acc[k] += __shfl_xor(acc[k], 8);
        acc[k] += __shfl_xor(acc[k], 16);
        acc[k] += __shfl_xor(acc[k], 32);
    }
    float inv = 1.f / (sm + DEPS);
    int c0 = l8 << 3;
    float4 bA = *(const float4*)&b1l[c0];
    float4 bB = *(const float4*)&b1l[c0 + 4];
    float v0 = fmaxf(fmaf(acc[0], inv, bA.x), 0.f);
    float v1 = fmaxf(fmaf(acc[1], inv, bA.y), 0.f);
    float v2 = fmaxf(fmaf(acc[2], inv, bA.z), 0.f);
    float v3 = fmaxf(fmaf(acc[3], inv, bA.w), 0.f);
    float v4 = fmaxf(fmaf(acc[4], inv, bB.x), 0.f);
    float v5 = fmaxf(fmaf(acc[5], inv, bB.y), 0.f);
    float v6 = fmaxf(fmaf(acc[6], inv, bB.z), 0.f);
    float v7 = fmaxf(fmaf(acc[7], inv, bB.w), 0.f);
    float4 wA0 = *(const float4*)&WxT[g8][c0];
    float4 wA1 = *(const float4*)&WxT[g8][c0 + 4];
    float4 wB0 = *(const float4*)&WxT[g8 + 8][c0];
    float4 wB1 = *(const float4*)&WxT[g8 + 8][c0 + 4];
    float rA = fmaf(v0, wA0.x, fmaf(v1, wA0.y, fmaf(v2, wA0.z, fmaf(v3, wA0.w,
               fmaf(v4, wA1.x, fmaf(v5, wA1.y, fmaf(v6, wA1.z, v7 * wA1.w)))))));
    float rB = fmaf(v0, wB0.x, fmaf(v1, wB0.y, fmaf(v2, wB0.z, fmaf(v3, wB0.w,
               fmaf(v4, wB1.x, fmaf(v5, wB1.y, fmaf(v6, wB1.z, v7 * wB1.w)))))));
    rA += __shfl_xor(rA, 1); rA += __shfl_xor(rA, 2); rA += __shfl_xor(rA, 4);
    rB += __shfl_xor(rB, 1); rB += __shfl_xor(rB, 2); rB += __shfl_xor(rB, 4);
    if (l8 == 0) {
        h2p[(size_t)d * 8 + g8] = rA;            // slots 0..6 = h2, 7 = as2
        if (g8 == 0) ad2[d] = rB;                // output 8 = ad2
    }
}

// fused layer-2 aggregate + bias. 8 lanes per row, 8 rows per wave.
__global__ __launch_bounds__(256) void f_agg2(
    const int* __restrict__ cnt, const unsigned* __restrict__ bkt,
    const uint2* __restrict__ ovf, const int* __restrict__ ovfn,
    const float* __restrict__ h2p, const float* __restrict__ ad2,
    const float* __restrict__ b2, float* __restrict__ out, int N)
{
    __shared__ float b2l[7];
    if (threadIdx.x < 7) b2l[threadIdx.x] = b2[threadIdx.x];
    __syncthreads();
    int lane = threadIdx.x & 63;
    int wv = threadIdx.x >> 6;
    int grp = lane >> 3, l8 = lane & 7;
    int d = blockIdx.x * 32 + wv * 8 + grp;
    bool valid = d < N;
    int lenf = 0; float adv = 0.f;
    if (valid) { lenf = cnt[d]; adv = ad2[d]; }
    int nc = min(lenf, CAP);
    size_t r0 = (size_t)d * CAP;
    float sm = 0.f;
    float a0 = 0.f, a1 = 0.f, a2 = 0.f, a3 = 0.f, a4 = 0.f, a5 = 0.f, a6 = 0.f;
    for (int p = l8; p < nc; p += 8) {
        unsigned u = bkt[r0 + p];
        int s = (int)(u >> 15);
        const float* hr = &h2p[(size_t)s * 8];
        float4 A = *(const float4*)hr;
        float4 B = *(const float4*)(hr + 4);
        float a = B.w + adv;
        a = (a > 0.f) ? a : 0.2f * a;
        float ea = __expf(a + dec_wt(u));
        sm += ea;
        a0 = fmaf(ea, A.x, a0); a1 = fmaf(ea, A.y, a1);
        a2 = fmaf(ea, A.z, a2); a3 = fmaf(ea, A.w, a3);
        a4 = fmaf(ea, B.x, a4); a5 = fmaf(ea, B.y, a5);
        a6 = fmaf(ea, B.z, a6);
    }
    if (lenf > CAP) {                            // rare overflow path
        int no = min(*ovfn, OVF_MAX);
        for (int i = l8; i < no; i += 8) {
            uint2 ov = ovf[i];
            if ((int)ov.x == d) {
                unsigned u = ov.y;
                int s = (int)(u >> 15);
                const float* hr = &h2p[(size_t)s * 8];
                float4 A = *(const float4*)hr;
                float4 B = *(const float4*)(hr + 4);
                float a = B.w + adv;
                a = (a > 0.f) ? a : 0.2f * a;
                float ea = __expf(a + dec_wt(u));
                sm += ea;
                a0 = fmaf(ea, A.x, a0); a1 = fmaf(ea, A.y, a1);
                a2 = fmaf(ea, A.z, a2); a3 = fmaf(ea, A.w, a3);
                a4 = fmaf(ea, B.x, a4); a5 = fmaf(ea, B.y, a5);
                a6 = fmaf(ea, B.z, a6);
            }
        }
    }
    #pragma unroll
    for (int o = 4; o; o >>= 1) {
        sm += __shfl_xor(sm, o);
        a0 += __shfl_xor(a0, o); a1 += __shfl_xor(a1, o);
        a2 += __shfl_xor(a2, o); a3 += __shfl_xor(a3, o);
        a4 += __shfl_xor(a4, o); a5 += __shfl_xor(a5, o);
        a6 += __shfl_xor(a6, o);
    }
    if (valid && l8 < 7) {
        float inv = 1.f / (sm + DEPS);
        float val = (l8 < 4) ? ((l8 < 2) ? (l8 ? a1 : a0) : ((l8 == 2) ? a2 : a3))
                             : ((l8 < 6) ? ((l8 == 4) ? a4 : a5) : a6);
        out[(size_t)d * 7 + l8] = fmaf(val, inv, b2l[l8]);
    }
}

// ============================== HOST ======================================

extern "C" void kernel_launch(void* const* d_in, const int* in_sizes, int n_in,
                              void* d_out, int out_size, void* d_ws, size_t ws_size,
                              hipStream_t stream) {
    const float* x   = (const float*)d_in[0];
    const int*   ei  = (const int*)d_in[1];
    const float* ew  = (const float*)d_in[2];
    const float* W1  = (const float*)d_in[3];
    const float* as1 = (const float*)d_in[4];
    const float* ad1 = (const float*)d_in[5];
    const float* b1  = (const float*)d_in[6];
    const float* W2  = (const float*)d_in[7];
    const float* a2s = (const float*)d_in[8];
    const float* a2d = (const float*)d_in[9];
    const float* b2  = (const float*)d_in[10];

    int N = in_sizes[0] / 128;
    int E = in_sizes[1] / 2;
    int T = E + N;
    const int* srcv = ei;
    const int* dstv = ei + E;
    float* out = (float*)d_out;

    int gT = (T + 255) / 256;

    // workspace (256B aligned): ~31.45 MB (R17-proven fit).
    // rank (6.8 MB) ALIASES h1: hist/scatB consume it before gemm1 writes h1.
    size_t A = 0;
    auto take = [&](size_t b) { size_t o = A; A = (A + b + 255) & ~(size_t)255; return o; };
    size_t o_h1   = take((size_t)N * 64 * 2);       // 12.8 MB (h1 | rank)
    size_t o_bkt  = take((size_t)N * CAP * 4);      // 12.8 MB
    size_t o_h2p  = take((size_t)N * 8 * 4);        //  3.2 MB padded (+as2)
    size_t o_ovf  = take((size_t)OVF_MAX * 8);      //  1.0 MB
    size_t o_cnt  = take((size_t)N * 4);            //  0.4 MB
    size_t o_ovfn = take(256);                      //  (contiguous after cnt)
    size_t o_asrc = take((size_t)N * 4);
    size_t o_adst = take((size_t)N * 4);
    size_t o_ad2  = take((size_t)N * 4);

    char* base = (char*)d_ws;
    bf16*     h1   = (bf16*)(base + o_h1);
    int*      rank = (int*)(base + o_h1);           // alias (consumed pre-gemm1)
    unsigned* bkt  = (unsigned*)(base + o_bkt);
    float*    h2p  = (float*)(base + o_h2p);
    uint2*    ovf  = (uint2*)(base + o_ovf);
    int*      cnt  = (int*)(base + o_cnt);
    int*      ovfn = (int*)(base + o_ovfn);
    float*    asrc = (float*)(base + o_asrc);
    float*    adst = (float*)(base + o_adst);
    float*    ad2  = (float*)(base + o_ad2);

    hipMemsetAsync(cnt, 0, (size_t)N * 4 + 256, stream);   // cnt + ovfn
    f_hist <<<gT, 256, 0, stream>>>(dstv, cnt, rank, E, T);
    f_scatB<<<gT, 256, 0, stream>>>(srcv, dstv, ew, rank, bkt, ovf, ovfn, E, T);
    f_gemm1<<<(N + 31) / 32, 256, 0, stream>>>(x, W1, as1, ad1, h1, asrc, adst, N);
    f_agg1<<<(N + 3) / 4, 256, 0, stream>>>(cnt, bkt, ovf, ovfn, asrc, adst, h1,
                                            b1, W2, a2s, a2d, h2p, ad2, N);
    f_agg2<<<(N + 31) / 32, 256, 0, stream>>>(cnt, bkt, ovf, ovfn, h2p, ad2, b2, out, N);
}